// Round 12
// baseline (570.490 us; speedup 1.0000x reference)
//
#include <hip/hip_runtime.h>
#include <hip/hip_bf16.h>

#define CUT 10
#define NB 256
#define NLAYERS 4
#define WSTRIDE 48

// slot map (each slot = padded 10x10 complex, 100 float2)
#define SLOT_S0 0
#define SLOT_DM 1      // 1024 displacement-prep matrices
#define SLOT_SQ 1025   // 16 squeezers (l*4+m)
#define SLOT_DS 1041   // 16 displacements (l*4+m)
#define SLOT_BS 1057   // 48 gates * 19 photon-number blocks
#define NSLOTS  1969

typedef __hip_bfloat16 bf16;

// physical (bank-swizzled) per-mode strides: ph = 1110*n0 + 111*n1 + 11*n2 + n3
#define F0 1110
#define F1 111
#define F2 11
#define F3 1
#define ST_PHYS 11100

// read element i of a buffer whose dtype (f32 vs bf16) was sniffed at runtime
__device__ __forceinline__ float readv(const void* p, int i, int isf32) {
  if (isf32) return ((const float*)p)[i];
  return __bfloat162float(((const bf16*)p)[i]);
}

// packed complex MAC with WAVE-UNIFORM u in SGPRs: acc += u * v.
// VOP3P allows one scalar (SGPR-pair) source -> zero v_mov overhead.
__device__ __forceinline__ void cmac_s(float2& a, float2 u, float2 v) {
  asm("v_pk_fma_f32 %0, %1, %2, %0 op_sel:[0,0,0] op_sel_hi:[0,1,1]\n\t"
      "v_pk_fma_f32 %0, %1, %2, %0 op_sel:[1,1,0] op_sel_hi:[1,0,1] neg_lo:[1,0,0]"
      : "+v"(a) : "s"(u), "v"(v));
}

// chunk permutation: wave w handles chunks g_perm[w][0..2]; chunk c: N=c/2,
// spec offset (c&1)*64. Balanced so per-wave sum(d^2) is ~84 (range 76..100).
__device__ const signed char g_perm[16][3] = {
  {18,-1,-1},{19,-1,-1},{16, 0,-1},{17, 1,-1},{20,36,-1},{21,37,-1},
  {14, 6,34},{15, 7,35},{22,30,-1},{23,31,-1},{12, 8, 4},{13, 9, 5},
  {24,28,32},{25,29,33},{10,26, 2},{11,27, 3}
};

// ------------------- K0: sniff input dtype -------------------
__global__ void sniff_dtype(const void* p, int n_elems, int* flag) {
  __shared__ float red[256];
  const unsigned short* h = (const unsigned short*)p;
  int t = threadIdx.x;
  float mx = 0.f;
  for (int i = t; i < n_elems; i += 256) {
    unsigned short u = h[i];
    bf16 bv = *(const bf16*)&u;
    float v = fabsf(__bfloat162float(bv));
    if (!(v < 1e30f)) v = 1e30f;
    mx = fmaxf(mx, v);
  }
  red[t] = mx;
  __syncthreads();
  for (int off = 128; off > 0; off >>= 1) {
    if (t < off) red[t] = fmaxf(red[t], red[t + off]);
    __syncthreads();
  }
  if (t == 0) *flag = (red[0] > 1000.f) ? 1 : 0;  // 1 => buffer is really f32
}

// ------------------- K1: build all generators -------------------
__global__ void build_gens(float2* slots, const void* inp, const void* w,
                           const int* flag) {
  int s = blockIdx.x;
  int t = threadIdx.x;
  if (t >= 100) return;
  int isf32 = *flag;
  int i = t / 10, j = t % 10;
  float2 val = make_float2(0.f, 0.f);
  if (s == SLOT_S0) {
    if (j == i + 2)      { float c = sqrtf((float)((i+1)*(i+2))); val.y = -0.25f*c; }
    else if (i == j + 2) { float c = sqrtf((float)((j+1)*(j+2))); val.y = -0.25f*c; }
  } else if (s < SLOT_SQ) {
    int k = s - SLOT_DM;
    float r = readv(inp, k, isf32);
    if (i == j + 1)      val.x =  r * sqrtf((float)(j+1));
    else if (j == i + 1) val.x = -r * sqrtf((float)(i+1));
  } else if (s < SLOT_DS) {
    int k = s - SLOT_SQ; int l = k >> 2; int m = k & 3;
    float r = readv(w, l*WSTRIDE + 16 + m, isf32);
    if (j == i + 2)      val.x =  0.5f*r*sqrtf((float)((i+1)*(i+2)));
    else if (i == j + 2) val.x = -0.5f*r*sqrtf((float)((j+1)*(j+2)));
  } else if (s < SLOT_BS) {
    int k = s - SLOT_DS; int l = k >> 2; int m = k & 3;
    float rd = readv(w, l*WSTRIDE + 36 + m, isf32);
    float ph = readv(w, l*WSTRIDE + 40 + m, isf32);
    float ar = rd * cosf(ph), ai = rd * sinf(ph);
    if (i == j + 1)      { float c = sqrtf((float)(j+1)); val.x =  ar*c; val.y = ai*c; }
    else if (j == i + 1) { float c = sqrtf((float)(i+1)); val.x = -ar*c; val.y = ai*c; }
  } else {
    int rel = s - SLOT_BS;
    int g = rel / 19; int N = rel % 19;
    int l = g / 12; int h = (g % 12) / 6; int p = g % 6;
    float th = readv(w, l*WSTRIDE + (h ? 20 : 0) + p, isf32);
    float ph = readv(w, l*WSTRIDE + (h ? 26 : 6) + p, isf32);
    int lo = max(0, N - 9), hi = min(9, N);
    int d = hi - lo + 1;
    if (i < d && j < d) {
      if (i == j + 1) {
        float c = sqrtf((float)((lo + j + 1) * (N - lo - j)));
        val.x = th * cosf(ph) * c; val.y = th * sinf(ph) * c;
      } else if (j == i + 1) {
        float c = sqrtf((float)((lo + i + 1) * (N - lo - i)));
        val.x = -th * cosf(ph) * c; val.y = th * sinf(ph) * c;
      }
    }
  }
  slots[(size_t)s * 100 + t] = val;
}

// ------------------- K2: generic expm (scaling-squaring + Taylor) -------------------
__global__ void expm_all(float2* slots) {
  __shared__ float2 T[100], P[100], R[100];
  __shared__ float rowsum[10];
  __shared__ int sshift;
  int s = blockIdx.x, t = threadIdx.x;
  int i = t / 10, j = t % 10;
  float2* G = slots + (size_t)s * 100;
  if (t < 100) T[t] = G[t];
  __syncthreads();
  if (t < 10) {
    float sum = 0.f;
    for (int c = 0; c < 10; ++c) { float2 z = T[t*10+c]; sum += fabsf(z.x) + fabsf(z.y); }
    rowsum[t] = sum;
  }
  __syncthreads();
  if (t == 0) {
    float nm = 0.f;
    for (int r = 0; r < 10; ++r) nm = fmaxf(nm, rowsum[r]);
    int sc = 0;
    if (!(nm < 1e6f)) sc = 0;
    else if (nm > 0.25f) sc = (int)ceilf(log2f(nm * 4.f));
    sshift = min(max(sc, 0), 40);
  }
  __syncthreads();
  int sh = sshift;
  float scl = ldexpf(1.f, -sh);
  if (t < 100) {
    float2 z = T[t]; z.x *= scl; z.y *= scl;
    T[t] = z; P[t] = z;
    R[t] = make_float2(z.x + (i == j ? 1.f : 0.f), z.y);
  }
  __syncthreads();
  for (int k = 2; k <= 12; ++k) {
    float2 acc = make_float2(0.f, 0.f);
    if (t < 100) {
      for (int c = 0; c < 10; ++c) {
        float2 a = P[i*10+c], b = T[c*10+j];
        acc.x += a.x*b.x - a.y*b.y;
        acc.y += a.x*b.y + a.y*b.x;
      }
      float inv = 1.f / (float)k;
      acc.x *= inv; acc.y *= inv;
    }
    __syncthreads();
    if (t < 100) { P[t] = acc; R[t].x += acc.x; R[t].y += acc.y; }
    __syncthreads();
  }
  for (int q = 0; q < sh; ++q) {
    float2 acc = make_float2(0.f, 0.f);
    if (t < 100) {
      for (int c = 0; c < 10; ++c) {
        float2 a = R[i*10+c], b = R[c*10+j];
        acc.x += a.x*b.x - a.y*b.y;
        acc.y += a.x*b.y + a.y*b.x;
      }
    }
    __syncthreads();
    if (t < 100) R[t] = acc;
    __syncthreads();
  }
  if (t < 100) G[t] = R[t];
}

// ---- BS gate: U read from GLOBAL via wave-uniform pointer (scalar pipe),
// state in LDS. Uniform control flow: dead lanes compute a dummy line
// (specc=min(spec,99)) and only stores are lane-guarded -> s_load eligible.
template<int sI, int sJ, int sA, int sB, bool FUSE>
__device__ __forceinline__ void bs_gate(
    float2* st, const float2* __restrict__ slots, int slotbase, int lane, int wv,
    float f0, float f1, float fdc, float f3)
{
  constexpr int step = sI - sJ;
#pragma unroll
  for (int r = 0; r < 3; ++r) {
    const int c = __builtin_amdgcn_readfirstlane((int)g_perm[wv][r]);
    if (c >= 0) {
      const int N  = c >> 1;
      const int lo = max(0, N - 9);
      const int sd = min(9, N) - lo + 1;          // uniform (derived from c)
      const float2* __restrict__ U = slots + (size_t)(slotbase + N) * 100;
      int spec  = ((c & 1) << 6) + lane;
      int specc = min(spec, 99);                  // dummy line for dead lanes
      int hi10 = specc / 10, lo10 = specc % 10;
      float2* base = st + hi10*sA + lo10*sB + lo*sI + (N - lo)*sJ;
      float angb = 0.f;
      if (FUSE)
        angb = f0*(float)hi10 + f1*(float)lo10 + f3*(float)N + fdc*(float)lo;
      float2 v[10];
#pragma unroll
      for (int k = 0; k < 10; ++k) if (k < sd) v[k] = base[k*step];
      const bool wr = (spec < 100);
#pragma unroll
      for (int rr = 0; rr < 10; ++rr) if (rr < sd) {
        float2 a0 = make_float2(0.f, 0.f), a1 = make_float2(0.f, 0.f);
        const float4* Urow = (const float4*)(U + rr*10);  // 16B-aligned rows
#pragma unroll
        for (int q = 0; q < 5; ++q) if (2*q < sd) {
          float4 uu = Urow[q];                    // uniform -> SGPRs via s_load
          cmac_s(a0, make_float2(uu.x, uu.y), v[2*q]);
          if (2*q + 1 < sd) cmac_s(a1, make_float2(uu.z, uu.w), v[2*q+1]);
        }
        float2 acc = make_float2(a0.x + a1.x, a0.y + a1.y);
        if (FUSE) {
          float sn, cs; sincosf(angb + fdc*(float)rr, &sn, &cs);
          acc = make_float2(acc.x*cs - acc.y*sn, acc.x*sn + acc.y*cs);
        }
        if (wr) base[rr*step] = acc;              // lane-guarded store only
      }
    }
  }
}

// ---- single-mode gate: U global/uniform (scalar pipe), dummy-line trick ----
template<int sM, int pA, int pB, int pC, bool KERR>
__device__ __forceinline__ void sm_gate(
    float2* st, const float2* __restrict__ U, int t,
    float k0, float k1, float k2, float k3)
{
  int line = min(t, 999);
  int q0 = line / 100, q1 = (line / 10) % 10, q2 = line % 10;
  float2* base = st + q0*pA + q1*pB + q2*pC;
  float angb = 0.f;
  if (KERR) angb = k0*(float)(q0*q0) + k1*(float)(q1*q1) + k2*(float)(q2*q2);
  float2 v[10];
#pragma unroll
  for (int k = 0; k < 10; ++k) v[k] = base[k*sM];
  const bool wr = (t < 1000);
#pragma unroll
  for (int rr = 0; rr < 10; ++rr) {
    float2 a0 = make_float2(0.f, 0.f), a1 = make_float2(0.f, 0.f);
    const float4* Urow = (const float4*)(U + rr*10);
#pragma unroll
    for (int q = 0; q < 5; ++q) {
      float4 uu = Urow[q];
      cmac_s(a0, make_float2(uu.x, uu.y), v[2*q]);
      cmac_s(a1, make_float2(uu.z, uu.w), v[2*q+1]);
    }
    float2 acc = make_float2(a0.x + a1.x, a0.y + a1.y);
    if (KERR) {
      float sn, cs; sincosf(angb + k3*(float)(rr*rr), &sn, &cs);
      acc = make_float2(acc.x*cs - acc.y*sn, acc.x*sn + acc.y*cs);
    }
    if (wr) base[rr*sM] = acc;
  }
}

// ------------------- K3: fused circuit — one block per batch, state in LDS -------------------
// LDS: state 88.8K + misc ~0.6K (U matrices now come via the scalar pipe).
__global__ __launch_bounds__(1024)
void fused_circuit(
    const float2* __restrict__ slots, const void* __restrict__ w,
    const int* __restrict__ flag, float* __restrict__ out)
{
  __shared__ float2 st[ST_PHYS];    // ~89 KB swizzled state
  __shared__ float2 psi[4][10];
  __shared__ float redw[64];
  const int b = blockIdx.x, t = threadIdx.x;
  const int wv = t >> 6, lane = t & 63;
  const int isf32 = *flag;

  // ---- initial product state ----
  if (t < 40) {
    int m = t / 10, r = t % 10;
    const float2* Dm = slots + (size_t)(SLOT_DM + b*4 + m) * 100;
    float2 acc = make_float2(0.f, 0.f);
    for (int c = 0; c < 10; ++c) {
      float2 a = Dm[r*10 + c];
      float2 vv = slots[(size_t)c * 10];   // S0 column 0
      acc.x += a.x*vv.x - a.y*vv.y;
      acc.y += a.x*vv.y + a.y*vv.x;
    }
    psi[m][r] = acc;
  }
  __syncthreads();
  for (int e = t; e < 10000; e += 1024) {
    int ph = e + e/10 + e/100;
    float2 z  = psi[0][e/1000];
    float2 w1 = psi[1][(e/100)%10];
    float2 r1 = make_float2(z.x*w1.x - z.y*w1.y, z.x*w1.y + z.y*w1.x);
    float2 w2 = psi[2][(e/10)%10];
    float2 r2 = make_float2(r1.x*w2.x - r1.y*w2.y, r1.x*w2.y + r1.y*w2.x);
    float2 w3 = psi[3][e%10];
    st[ph] = make_float2(r2.x*w3.x - r2.y*w3.y, r2.x*w3.y + r2.y*w3.x);
  }
  __syncthreads();

  // ---- circuit ----
#pragma unroll 1
  for (int l = 0; l < NLAYERS; ++l) {
#pragma unroll 1
    for (int half = 0; half < 2; ++half) {
      const int g6 = l*12 + half*6;
      int foff = l*WSTRIDE + (half ? 32 : 12);
      float f0 = readv(w, foff+0, isf32), f1 = readv(w, foff+1, isf32);
      float f2v = readv(w, foff+2, isf32), f3 = readv(w, foff+3, isf32);
      float fdc = f2v - f3;

      bs_gate<F0,F1,F2,F3,false>(st, slots, SLOT_BS+(g6+0)*19, lane, wv, 0,0,0,0);
      __syncthreads();
      bs_gate<F0,F2,F1,F3,false>(st, slots, SLOT_BS+(g6+1)*19, lane, wv, 0,0,0,0);
      __syncthreads();
      bs_gate<F0,F3,F1,F2,false>(st, slots, SLOT_BS+(g6+2)*19, lane, wv, 0,0,0,0);
      __syncthreads();
      bs_gate<F1,F2,F0,F3,false>(st, slots, SLOT_BS+(g6+3)*19, lane, wv, 0,0,0,0);
      __syncthreads();
      bs_gate<F1,F3,F0,F2,false>(st, slots, SLOT_BS+(g6+4)*19, lane, wv, 0,0,0,0);
      __syncthreads();
      bs_gate<F2,F3,F0,F1,true >(st, slots, SLOT_BS+(g6+5)*19, lane, wv, f0,f1,fdc,f3);
      __syncthreads();

      const int ub_ = (half == 0) ? (l*4) : (16 + l*4);
      float k0=0.f, k1=0.f, k2=0.f, k3=0.f;
      if (half == 1) {
        int koff = l*WSTRIDE + 44;
        k0 = readv(w, koff+0, isf32); k1 = readv(w, koff+1, isf32);
        k2 = readv(w, koff+2, isf32); k3 = readv(w, koff+3, isf32);
      }
      const float2* smU = slots + (size_t)SLOT_SQ * 100;
      sm_gate<F0,F1,F2,F3,false>(st, smU+(ub_+0)*100, t, 0,0,0,0);
      __syncthreads();
      sm_gate<F1,F0,F2,F3,false>(st, smU+(ub_+1)*100, t, 0,0,0,0);
      __syncthreads();
      sm_gate<F2,F0,F1,F3,false>(st, smU+(ub_+2)*100, t, 0,0,0,0);
      __syncthreads();
      if (half == 1)
        sm_gate<F3,F0,F1,F2,true >(st, smU+(ub_+3)*100, t, k0,k1,k2,k3);
      else
        sm_gate<F3,F0,F1,F2,false>(st, smU+(ub_+3)*100, t, 0,0,0,0);
      __syncthreads();
    }
  }

  // ---- photon-number expectations (wave shuffle reduce) ----
  float a0 = 0.f, a1 = 0.f, a2 = 0.f, a3 = 0.f;
  for (int e = t; e < 10000; e += 1024) {
    int ph = e + e/10 + e/100;
    float2 z = st[ph];
    float pz = z.x*z.x + z.y*z.y;
    a0 += pz * (float)(e/1000);
    a1 += pz * (float)((e/100)%10);
    a2 += pz * (float)((e/10)%10);
    a3 += pz * (float)(e%10);
  }
  for (int off2 = 32; off2 > 0; off2 >>= 1) {
    a0 += __shfl_down(a0, off2, 64);
    a1 += __shfl_down(a1, off2, 64);
    a2 += __shfl_down(a2, off2, 64);
    a3 += __shfl_down(a3, off2, 64);
  }
  if (lane == 0) {
    redw[wv*4+0] = a0; redw[wv*4+1] = a1;
    redw[wv*4+2] = a2; redw[wv*4+3] = a3;
  }
  __syncthreads();
  if (t < 4) {
    float s = 0.f;
    for (int ww = 0; ww < 16; ++ww) s += redw[ww*4 + t];
    out[b*4 + t] = s;
  }
}

extern "C" void kernel_launch(void* const* d_in, const int* in_sizes, int n_in,
                              void* d_out, int out_size, void* d_ws, size_t ws_size,
                              hipStream_t stream) {
  const void* inp = d_in[0];
  const void* w   = d_in[1];
  float* out = (float*)d_out;           // reference output dtype is float32
  int*    flag  = (int*)d_ws;           // 16-byte header
  float2* slots = (float2*)((char*)d_ws + 16);

  sniff_dtype<<<dim3(1), dim3(256), 0, stream>>>(inp, in_sizes[0], flag);
  build_gens<<<dim3(NSLOTS), dim3(128), 0, stream>>>(slots, inp, w, flag);
  expm_all<<<dim3(NSLOTS), dim3(128), 0, stream>>>(slots);
  fused_circuit<<<dim3(NB), dim3(1024), 0, stream>>>(slots, w, flag, out);
}